// Round 10
// baseline (124.730 us; speedup 1.0000x reference)
//
#include <hip/hip_runtime.h>
#include <stdint.h>

#define DD 128                 // drug feature dim
#define HH 32                  // hidden dim
#define RS 36                  // f16 per h-row (72 B): 18m mod 32 all-distinct -> conflict-free
#define GRP 1040               // stage DMA-group stride: 1 KB data + 16 B pad (bank spread)
#define TABQ (4096 * DD / 4)   // float4 count of drug table
#define BLOB_OFF (1u << 20)    // weight fragment blob offset inside d_ws (bytes)

typedef _Float16 f16;
typedef _Float16 f16x4 __attribute__((ext_vector_type(4)));
typedef _Float16 f16x8 __attribute__((ext_vector_type(8)));
typedef float    f32x4 __attribute__((ext_vector_type(4)));

#define GL1(p)  ((const __attribute__((address_space(1))) void*)(p))
#define LDS3(p) ((__attribute__((address_space(3))) void*)(p))

// Pre-pass: (a) drug table f32->f16 (blocks 0..511); (b) weight-fragment blob
// at ws+1MB (block 512): W1 slots 0..511, W2 512..639, W3 640..767,
// W4-column-fragment 768..831 (lane m==0 holds W4[8q+j], else 0).
__global__ __launch_bounds__(256)
void synergy_prepass(const float* __restrict__ drug,
                     const float* __restrict__ W1, const float* __restrict__ W2,
                     const float* __restrict__ W3, const float* __restrict__ W4,
                     f16* __restrict__ tab)
{
    const int tid = threadIdx.x;
    if ((int)blockIdx.x == 512) {
        f16x8* __restrict__ blob16 = (f16x8*)((char*)tab + BLOB_OFF);
        const float4* __restrict__ W1v = (const float4*)W1;
        #pragma unroll
        for (int p = 0; p < 2; ++p) {
            const int S = p * 256 + tid;
            const int t = S >> 8, f = (S >> 6) & 3, l = S & 63;
            const int mm = l & 15, qq = l >> 4;
            const int c4 = (t * 16 + mm) * (DD / 4) + f * 8 + qq * 2;
            const float4 w0 = W1v[c4], w1 = W1v[c4 + 1];
            f16x8 r;
            r[0]=(f16)w0.x; r[1]=(f16)w0.y; r[2]=(f16)w0.z; r[3]=(f16)w0.w;
            r[4]=(f16)w1.x; r[5]=(f16)w1.y; r[6]=(f16)w1.z; r[7]=(f16)w1.w;
            blob16[S] = r;
        }
        {
            const int B = tid & 127;
            const int t = B >> 6, l = B & 63;
            const int mm = l & 15, qq = l >> 4;
            const int c4 = (t * 16 + mm) * (HH / 4) + qq * 2;
            const float4* __restrict__ src = (tid < 128) ? (const float4*)W2 : (const float4*)W3;
            const float4 w0 = src[c4], w1 = src[c4 + 1];
            f16x8 r;
            r[0]=(f16)w0.x; r[1]=(f16)w0.y; r[2]=(f16)w0.z; r[3]=(f16)w0.w;
            r[4]=(f16)w1.x; r[5]=(f16)w1.y; r[6]=(f16)w1.z; r[7]=(f16)w1.w;
            blob16[512 + (tid & 128) + B] = r;
        }
        if (tid < 64) {                         // W4 column fragment
            const int mm = tid & 15, qq = tid >> 4;
            f16x8 r;
            #pragma unroll
            for (int j = 0; j < 8; ++j)
                r[j] = (mm == 0) ? (f16)W4[qq * 8 + j] : (f16)0.0f;
            blob16[768 + tid] = r;
        }
        return;
    }
    const int i = blockIdx.x * 256 + tid;
    if (i < TABQ) {
        const float4 v = ((const float4*)drug)[i];
        f16x4 h;
        h[0]=(f16)v.x; h[1]=(f16)v.y; h[2]=(f16)v.z; h[3]=(f16)v.w;
        ((f16x4*)tab)[i] = h;
    }
}

// Main: persistent tail-issue pipeline (r9 structure) with COALESCING-FIRST
// gather swizzle: within each 16-lane row read, lane-quads fetch whole
// 64B-aligned chunks (chunk rotated per row: seg = 4*(((j>>2)+row)&3)+(j&3))
// -> 4 lanes merge per L1 line access (vs 1 with byte-rotation). LDS bank
// spread for the readback comes from a 16B pad per 1KB DMA group (stride
// 1040B): phase-A b128 reads are exactly 2-way -> free.
__global__ __launch_bounds__(256, 2)
void synergy_main(const f16* __restrict__ tab, const int* __restrict__ edges,
                  const float* __restrict__ b1, const float* __restrict__ b2,
                  const float* __restrict__ b3, const float* __restrict__ b4,
                  float* __restrict__ out, int E, int NG)
{
    __shared__ __align__(16) f16 stage[4][12 * GRP / 2]; // 12 groups x 1040 B per wave
    __shared__ __align__(16) f16 hbuf[4][16 * RS];       // 4.5 KiB per block

    const int tid  = threadIdx.x;
    const int wave = tid >> 6;
    const int lane = tid & 63;
    const int m    = lane & 15;
    const int q    = lane >> 4;

    const int WSTR = (int)gridDim.x * 4;
    int g = (int)blockIdx.x * 4 + wave;
    if (g >= NG) return;

    const char* __restrict__ tabB   = (const char*)tab;
    const int4* __restrict__ edges4 = (const int4*)edges;

    // ---- per-wave constants: weights (pre-swizzled blob, L2 broadcast), biases
    const f16x8* __restrict__ blobG = (const f16x8*)(tabB + BLOB_OFF);
    f16x8 wa[2][4];
    #pragma unroll
    for (int t = 0; t < 2; ++t)
        #pragma unroll
        for (int f = 0; f < 4; ++f)
            wa[t][f] = blobG[(t * 4 + f) * 64 + lane];
    const f16x8 w2a = blobG[512 + lane], w2b = blobG[576 + lane];
    const f16x8 w3a = blobG[640 + lane], w3b = blobG[704 + lane];
    const f16x8 wf4 = blobG[768 + lane];
    const float b1a = b1[m], b1b = b1[16 + m];
    const float b2a = b2[m], b2b = b2[16 + m];
    const float b3a = b3[m], b3b = b3[16 + m];
    const float b4v = b4[0];

    f16* __restrict__ stg = stage[wave];
    f16* __restrict__ hb  = hbuf[wave];

    auto load_ed = [&](int gg) -> int4 {
        int e = (gg << 4) + m;
        e = (e < E) ? e : (E - 1);
        return edges4[e];
    };
    // DMA (t,gg): lane (q=l>>4 row-in-quad, j=l&15 slot) stages row 4gg+q of
    // table t; fetches global 64B-chunk-rotated segment -> quad-coalesced.
    // LDS dest: group (t*4+gg)*GRP + l*16 (HW: uniform base + lane*16).
    const int seg16 = (4 * (((m >> 2) + q) & 3) + (m & 3)) << 4;  // j == m
    auto issue_dma = [&](const int4 ed) {
        int rowb[12];
        #pragma unroll
        for (int gg = 0; gg < 4; ++gg) {
            const int src = 4 * gg + q;
            rowb[0 * 4 + gg] = __shfl(ed.x, src, 64) << 8;
            rowb[1 * 4 + gg] = __shfl(ed.y, src, 64) << 8;
            rowb[2 * 4 + gg] = __shfl(ed.z, src, 64) << 8;
        }
        __builtin_amdgcn_sched_barrier(0);
        #pragma unroll
        for (int t = 0; t < 3; ++t)
            #pragma unroll
            for (int gg = 0; gg < 4; ++gg)
                __builtin_amdgcn_global_load_lds(
                    GL1(tabB + (size_t)(rowb[t * 4 + gg] + seg16)),
                    LDS3((char*)stg + (t * 4 + gg) * GRP), 16, 0, 0);
    };

    // ---- prologue
    int4 ed_cur = load_ed(g);
    issue_dma(ed_cur);
    int gn = g + WSTR;
    int4 ed_nxt = load_ed((gn < NG) ? gn : g);

    // Phase-A readback: row m of table t lives in group t*4+(m>>2), local row
    // m&3; data chunk f sits at slot-chunk (f-(m&3))&3, within-chunk q.
    const int baseA = (m >> 2) * GRP + (m & 3) * 256 + (q << 4);
    const int rotm  = m & 3;

    for (;;) {
        __builtin_amdgcn_s_waitcnt(0x0F70);     // vmcnt(0): stage DMAs landed
        __builtin_amdgcn_sched_barrier(0);

        // ---- Phase A: L1 (8 MFMAs, K=128); consumes stage
        f32x4 acc0 = {b1a, b1a, b1a, b1a};
        f32x4 acc1 = {b1b, b1b, b1b, b1b};
        #pragma unroll
        for (int f = 0; f < 4; ++f) {
            const int off = baseA + (((f - rotm) & 3) << 6);
            const f16x8 v0 = *(const f16x8*)((char*)stg + off);
            const f16x8 v1 = *(const f16x8*)((char*)stg + off + 4 * GRP);
            const f16x8 v2 = *(const f16x8*)((char*)stg + off + 8 * GRP);
            const f16x8 p = v0 * v1 * v2;
            acc0 = __builtin_amdgcn_mfma_f32_16x16x32_f16(p, wa[0][f], acc0, 0, 0, 0);
            acc1 = __builtin_amdgcn_mfma_f32_16x16x32_f16(p, wa[1][f], acc1, 0, 0, 0);
        }
        #pragma unroll
        for (int r = 0; r < 4; ++r) {
            const int row = 4 * q + r;
            hb[row * RS + m]      = (f16)fmaxf(acc0[r], 0.0f);
            hb[row * RS + 16 + m] = (f16)fmaxf(acc1[r], 0.0f);
        }

        // ---- prefetch edges two groups ahead (register; drained next top-wait)
        const int gf = gn + WSTR;
        const int4 ed_fut = load_ed((gf < NG) ? gf : g);

        // ---- Phase B: L2
        {
            const f16x8 a2 = *(const f16x8*)(hb + m * RS + q * 8);
            f32x4 c0 = {b2a, b2a, b2a, b2a};
            f32x4 c1 = {b2b, b2b, b2b, b2b};
            c0 = __builtin_amdgcn_mfma_f32_16x16x32_f16(a2, w2a, c0, 0, 0, 0);
            c1 = __builtin_amdgcn_mfma_f32_16x16x32_f16(a2, w2b, c1, 0, 0, 0);
            #pragma unroll
            for (int r = 0; r < 4; ++r) {
                const int row = 4 * q + r;
                hb[row * RS + m]      = (f16)fmaxf(c0[r], 0.0f);
                hb[row * RS + 16 + m] = (f16)fmaxf(c1[r], 0.0f);
            }
        }

        // ---- Phase C: L3 (h3 back to LDS for L4's A-operand)
        {
            const f16x8 a3 = *(const f16x8*)(hb + m * RS + q * 8);
            f32x4 d0 = {b3a, b3a, b3a, b3a};
            f32x4 d1 = {b3b, b3b, b3b, b3b};
            d0 = __builtin_amdgcn_mfma_f32_16x16x32_f16(a3, w3a, d0, 0, 0, 0);
            d1 = __builtin_amdgcn_mfma_f32_16x16x32_f16(a3, w3b, d1, 0, 0, 0);
            #pragma unroll
            for (int r = 0; r < 4; ++r) {
                const int row = 4 * q + r;
                hb[row * RS + m]      = (f16)fmaxf(d0[r], 0.0f);
                hb[row * RS + 16 + m] = (f16)fmaxf(d1[r], 0.0f);
            }
        }

        // ---- Phase D: L4 as MFMA vs zero-padded W4 column; col 0 = result
        {
            const f16x8 a4 = *(const f16x8*)(hb + m * RS + q * 8);
            f32x4 z = {b4v, b4v, b4v, b4v};
            z = __builtin_amdgcn_mfma_f32_16x16x32_f16(a4, wf4, z, 0, 0, 0);
            if (m == 0) {                        // lanes 0,16,32,48: rows 4q..4q+3
                const int e0 = (g << 4) + 4 * q;
                float4 res;
                res.x = 1.0f / (1.0f + __expf(-z[0]));
                res.y = 1.0f / (1.0f + __expf(-z[1]));
                res.z = 1.0f / (1.0f + __expf(-z[2]));
                res.w = 1.0f / (1.0f + __expf(-z[3]));
                if (e0 + 3 < E) *(float4*)(out + e0) = res;
                else {
                    if (e0 + 0 < E) out[e0 + 0] = res.x;
                    if (e0 + 1 < E) out[e0 + 1] = res.y;
                    if (e0 + 2 < E) out[e0 + 2] = res.z;
                }
            }
        }
        // label pass-through
        const int eL = (g << 4) + lane;
        if (lane < 16 && eL < E) out[E + eL] = (float)ed_cur.w;

        // ---- TAIL: issue next group's DMAs (nothing after this reads LDS)
        if (gn >= NG) break;
        issue_dma(ed_nxt);
        g = gn; gn = gf; ed_cur = ed_nxt; ed_nxt = ed_fut;
    }
}

extern "C" void kernel_launch(void* const* d_in, const int* in_sizes, int n_in,
                              void* d_out, int out_size, void* d_ws, size_t ws_size,
                              hipStream_t stream)
{
    const float* drug  = (const float*)d_in[0];
    // d_in[1] (cell_hidden_out), d_in[3] (proj_W), d_in[4] (proj_b): dead code
    const int*   edges = (const int*)d_in[2];
    const float* W1 = (const float*)d_in[5];
    const float* b1 = (const float*)d_in[6];
    const float* W2 = (const float*)d_in[7];
    const float* b2 = (const float*)d_in[8];
    const float* W3 = (const float*)d_in[9];
    const float* b3 = (const float*)d_in[10];
    const float* W4 = (const float*)d_in[11];
    const float* b4 = (const float*)d_in[12];
    float* out = (float*)d_out;
    f16*   tab = (f16*)d_ws;   // [0,1MB): f16 table; [1MB,+13KB): weight blob

    const int E  = in_sizes[2] / 4;
    const int NG = (E + 15) / 16;

    hipLaunchKernelGGL(synergy_prepass, dim3(513), dim3(256), 0, stream,
                       drug, W1, W2, W3, W4, tab);
    int blocks = (NG + 3) / 4;
    if (blocks > 512) blocks = 512;          // 2 blocks/CU x 256 CUs (54.5KB LDS)
    hipLaunchKernelGGL(synergy_main, dim3(blocks), dim3(256), 0, stream,
                       tab, edges, b1, b2, b3, b4, out, E, NG);
}

// Round 11
// 122.916 us; speedup vs baseline: 1.0148x; 1.0148x over previous
//
#include <hip/hip_runtime.h>
#include <stdint.h>

#define DD 128                 // drug feature dim
#define HH 32                  // hidden dim
#define RS 36                  // f16 per h-row (72 B)
#define TABQ (4096 * DD / 4)   // float4 count of drug table
#define BLOB_OFF (1u << 20)    // weight fragment blob offset inside d_ws (bytes)

typedef _Float16 f16;
typedef _Float16 f16x4 __attribute__((ext_vector_type(4)));
typedef _Float16 f16x8 __attribute__((ext_vector_type(8)));
typedef float    f32x4 __attribute__((ext_vector_type(4)));

// Pre-pass: (a) drug table f32->f16 (blocks 0..511); (b) weight-fragment blob
// at ws+1MB (block 512): W1 slots 0..511, W2 512..639, W3 640..767,
// W4-column-fragment 768..831 (lane m==0 holds W4[8q+j], else 0).
__global__ __launch_bounds__(256)
void synergy_prepass(const float* __restrict__ drug,
                     const float* __restrict__ W1, const float* __restrict__ W2,
                     const float* __restrict__ W3, const float* __restrict__ W4,
                     f16* __restrict__ tab)
{
    const int tid = threadIdx.x;
    if ((int)blockIdx.x == 512) {
        f16x8* __restrict__ blob16 = (f16x8*)((char*)tab + BLOB_OFF);
        const float4* __restrict__ W1v = (const float4*)W1;
        #pragma unroll
        for (int p = 0; p < 2; ++p) {
            const int S = p * 256 + tid;
            const int t = S >> 8, f = (S >> 6) & 3, l = S & 63;
            const int mm = l & 15, qq = l >> 4;
            const int c4 = (t * 16 + mm) * (DD / 4) + f * 8 + qq * 2;
            const float4 w0 = W1v[c4], w1 = W1v[c4 + 1];
            f16x8 r;
            r[0]=(f16)w0.x; r[1]=(f16)w0.y; r[2]=(f16)w0.z; r[3]=(f16)w0.w;
            r[4]=(f16)w1.x; r[5]=(f16)w1.y; r[6]=(f16)w1.z; r[7]=(f16)w1.w;
            blob16[S] = r;
        }
        {
            const int B = tid & 127;
            const int t = B >> 6, l = B & 63;
            const int mm = l & 15, qq = l >> 4;
            const int c4 = (t * 16 + mm) * (HH / 4) + qq * 2;
            const float4* __restrict__ src = (tid < 128) ? (const float4*)W2 : (const float4*)W3;
            const float4 w0 = src[c4], w1 = src[c4 + 1];
            f16x8 r;
            r[0]=(f16)w0.x; r[1]=(f16)w0.y; r[2]=(f16)w0.z; r[3]=(f16)w0.w;
            r[4]=(f16)w1.x; r[5]=(f16)w1.y; r[6]=(f16)w1.z; r[7]=(f16)w1.w;
            blob16[512 + (tid & 128) + B] = r;
        }
        if (tid < 64) {                         // W4 column fragment
            const int mm = tid & 15, qq = tid >> 4;
            f16x8 r;
            #pragma unroll
            for (int j = 0; j < 8; ++j)
                r[j] = (mm == 0) ? (f16)W4[qq * 8 + j] : (f16)0.0f;
            blob16[768 + tid] = r;
        }
        return;
    }
    const int i = blockIdx.x * 256 + tid;
    if (i < TABQ) {
        const float4 v = ((const float4*)drug)[i];
        f16x4 h;
        h[0]=(f16)v.x; h[1]=(f16)v.y; h[2]=(f16)v.z; h[3]=(f16)v.w;
        ((f16x4*)tab)[i] = h;
    }
}

// Main: persistent loop; gather via plain VGPR loads with ADJACENT-LANE line
// sharing (instr s: lane l reads row 4(s&3)+(l>>4), seg l&15 -> each 16-lane
// beat = 4 aligned 64B lines, 4 lanes each -> TA merge), then ds_write_b128
// scatter into a 272B-stride stage (2-way conflicts only). Next group's loads
// issue right after the ds_writes free the registers -> phases cover latency.
// 4 MFMA layers; L4 via zero-padded W4 column fragment. Barrier-free.
__global__ __launch_bounds__(256, 4)
void synergy_main(const f16* __restrict__ tab, const int* __restrict__ edges,
                  const float* __restrict__ b1, const float* __restrict__ b2,
                  const float* __restrict__ b3, const float* __restrict__ b4,
                  float* __restrict__ out, int E, int NG)
{
    // per-wave stage: 12 blocks x (4 rows x 272B) = 13056 B; hbuf overlays start
    __shared__ __align__(16) f16 stage[4][12 * 1088 / 2];

    const int tid  = threadIdx.x;
    const int wave = tid >> 6;
    const int lane = tid & 63;
    const int m    = lane & 15;    // consumer: MFMA row
    const int q    = lane >> 4;    // consumer: quad
    const int mq   = lane >> 4;    // loader: row-in-block
    const int sg   = lane & 15;    // loader: 16B segment

    const int WSTR = (int)gridDim.x * 4;
    int g = (int)blockIdx.x * 4 + wave;
    if (g >= NG) return;

    const char* __restrict__ tabB   = (const char*)tab;
    const int4* __restrict__ edges4 = (const int4*)edges;

    // ---- per-wave constants: weights (pre-swizzled blob, L2 broadcast), biases
    const f16x8* __restrict__ blobG = (const f16x8*)(tabB + BLOB_OFF);
    f16x8 wa[2][4];
    #pragma unroll
    for (int t = 0; t < 2; ++t)
        #pragma unroll
        for (int f = 0; f < 4; ++f)
            wa[t][f] = blobG[(t * 4 + f) * 64 + lane];
    const f16x8 w2a = blobG[512 + lane], w2b = blobG[576 + lane];
    const f16x8 w3a = blobG[640 + lane], w3b = blobG[704 + lane];
    const f16x8 wf4 = blobG[768 + lane];
    const float b1a = b1[m], b1b = b1[16 + m];
    const float b2a = b2[m], b2b = b2[16 + m];
    const float b3a = b3[m], b3b = b3[16 + m];
    const float b4v = b4[0];

    f16* __restrict__ stg = stage[wave];
    f16* __restrict__ hb  = stg;          // overlay: safe per in-order LDS pipe

    auto load_ed = [&](int gg) -> int4 {
        int e = (gg << 4) + m;
        e = (e < E) ? e : (E - 1);
        return edges4[e];
    };
    // Coalesced gather: instr s (t=s>>2): lane reads row 4(s&3)+mq, seg sg.
    f16x8 dat[12];
    auto issue_loads = [&](const int4 ed) {
        #pragma unroll
        for (int s = 0; s < 12; ++s) {
            const int src = 4 * (s & 3) + mq;
            const int t = s >> 2;
            const int row = (t == 0) ? __shfl(ed.x, src, 64)
                          : (t == 1) ? __shfl(ed.y, src, 64)
                                     : __shfl(ed.z, src, 64);
            dat[s] = *(const f16x8*)(tabB + ((size_t)row << 8) + (sg << 4));
        }
    };

    // ---- prologue
    int4 ed_cur = load_ed(g);
    issue_loads(ed_cur);
    int gn = g + WSTR;
    int4 ed_nxt = load_ed((gn < NG) ? gn : g);

    const int woff  = mq * 272 + sg * 16;                         // write offset
    const int rbase = (m >> 2) * 1088 + (m & 3) * 272 + (q << 4); // read base

    for (;;) {
        // ---- park group g's rows in stage (per-lane scatter; fine-grained vmcnt)
        #pragma unroll
        for (int s = 0; s < 12; ++s)
            *(f16x8*)((char*)stg + s * 1088 + woff) = dat[s];

        // ---- immediately issue next group's loads (regs freed by the writes);
        //      phases below (~600 cy) cover the L2 flight
        issue_loads(ed_nxt);
        const int gf = gn + WSTR;
        const int4 ed_fut = load_ed((gf < NG) ? gf : g);

        // ---- Phase A: L1 (8 MFMAs, K=128)
        f32x4 acc0 = {b1a, b1a, b1a, b1a};
        f32x4 acc1 = {b1b, b1b, b1b, b1b};
        #pragma unroll
        for (int f = 0; f < 4; ++f) {
            const int off = rbase + f * 64;
            const f16x8 v0 = *(const f16x8*)((char*)stg + off);
            const f16x8 v1 = *(const f16x8*)((char*)stg + off + 4352);
            const f16x8 v2 = *(const f16x8*)((char*)stg + off + 8704);
            const f16x8 p = v0 * v1 * v2;
            acc0 = __builtin_amdgcn_mfma_f32_16x16x32_f16(p, wa[0][f], acc0, 0, 0, 0);
            acc1 = __builtin_amdgcn_mfma_f32_16x16x32_f16(p, wa[1][f], acc1, 0, 0, 0);
        }
        #pragma unroll
        for (int r = 0; r < 4; ++r) {
            const int row = 4 * q + r;
            hb[row * RS + m]      = (f16)fmaxf(acc0[r], 0.0f);
            hb[row * RS + 16 + m] = (f16)fmaxf(acc1[r], 0.0f);
        }

        // ---- Phase B: L2
        {
            const f16x8 a2 = *(const f16x8*)(hb + m * RS + q * 8);
            f32x4 c0 = {b2a, b2a, b2a, b2a};
            f32x4 c1 = {b2b, b2b, b2b, b2b};
            c0 = __builtin_amdgcn_mfma_f32_16x16x32_f16(a2, w2a, c0, 0, 0, 0);
            c1 = __builtin_amdgcn_mfma_f32_16x16x32_f16(a2, w2b, c1, 0, 0, 0);
            #pragma unroll
            for (int r = 0; r < 4; ++r) {
                const int row = 4 * q + r;
                hb[row * RS + m]      = (f16)fmaxf(c0[r], 0.0f);
                hb[row * RS + 16 + m] = (f16)fmaxf(c1[r], 0.0f);
            }
        }

        // ---- Phase C: L3 (h3 back to LDS for L4's A-operand)
        {
            const f16x8 a3 = *(const f16x8*)(hb + m * RS + q * 8);
            f32x4 d0 = {b3a, b3a, b3a, b3a};
            f32x4 d1 = {b3b, b3b, b3b, b3b};
            d0 = __builtin_amdgcn_mfma_f32_16x16x32_f16(a3, w3a, d0, 0, 0, 0);
            d1 = __builtin_amdgcn_mfma_f32_16x16x32_f16(a3, w3b, d1, 0, 0, 0);
            #pragma unroll
            for (int r = 0; r < 4; ++r) {
                const int row = 4 * q + r;
                hb[row * RS + m]      = (f16)fmaxf(d0[r], 0.0f);
                hb[row * RS + 16 + m] = (f16)fmaxf(d1[r], 0.0f);
            }
        }

        // ---- Phase D: L4 as MFMA vs zero-padded W4 column; col 0 = result
        {
            const f16x8 a4 = *(const f16x8*)(hb + m * RS + q * 8);
            f32x4 z = {b4v, b4v, b4v, b4v};
            z = __builtin_amdgcn_mfma_f32_16x16x32_f16(a4, wf4, z, 0, 0, 0);
            if (m == 0) {                        // lanes 0,16,32,48: rows 4q..4q+3
                const int e0 = (g << 4) + 4 * q;
                float4 res;
                res.x = 1.0f / (1.0f + __expf(-z[0]));
                res.y = 1.0f / (1.0f + __expf(-z[1]));
                res.z = 1.0f / (1.0f + __expf(-z[2]));
                res.w = 1.0f / (1.0f + __expf(-z[3]));
                if (e0 + 3 < E) *(float4*)(out + e0) = res;
                else {
                    if (e0 + 0 < E) out[e0 + 0] = res.x;
                    if (e0 + 1 < E) out[e0 + 1] = res.y;
                    if (e0 + 2 < E) out[e0 + 2] = res.z;
                }
            }
        }
        // label pass-through
        const int eL = (g << 4) + lane;
        if (lane < 16 && eL < E) out[E + eL] = (float)ed_cur.w;

        if (gn >= NG) break;
        g = gn; gn = gf; ed_cur = ed_nxt; ed_nxt = ed_fut;
    }
}

extern "C" void kernel_launch(void* const* d_in, const int* in_sizes, int n_in,
                              void* d_out, int out_size, void* d_ws, size_t ws_size,
                              hipStream_t stream)
{
    const float* drug  = (const float*)d_in[0];
    // d_in[1] (cell_hidden_out), d_in[3] (proj_W), d_in[4] (proj_b): dead code
    const int*   edges = (const int*)d_in[2];
    const float* W1 = (const float*)d_in[5];
    const float* b1 = (const float*)d_in[6];
    const float* W2 = (const float*)d_in[7];
    const float* b2 = (const float*)d_in[8];
    const float* W3 = (const float*)d_in[9];
    const float* b3 = (const float*)d_in[10];
    const float* W4 = (const float*)d_in[11];
    const float* b4 = (const float*)d_in[12];
    float* out = (float*)d_out;
    f16*   tab = (f16*)d_ws;   // [0,1MB): f16 table; [1MB,+13KB): weight blob

    const int E  = in_sizes[2] / 4;
    const int NG = (E + 15) / 16;

    hipLaunchKernelGGL(synergy_prepass, dim3(513), dim3(256), 0, stream,
                       drug, W1, W2, W3, W4, tab);
    int blocks = (NG + 3) / 4;
    if (blocks > 768) blocks = 768;          // up to 3 blocks/CU (52.2KB LDS)
    hipLaunchKernelGGL(synergy_main, dim3(blocks), dim3(256), 0, stream,
                       tab, edges, b1, b2, b3, b4, out, E, NG);
}